// Round 13
// baseline (263.907 us; speedup 1.0000x reference)
//
#include <hip/hip_runtime.h>
#include <hip/hip_bf16.h>

#define N_NODES 100000
#define HID 128
#define BB 64
#define CC 16
#define LL 256

typedef __bf16 b16x8 __attribute__((ext_vector_type(8)));
typedef float f32x4 __attribute__((ext_vector_type(4)));

__device__ __forceinline__ unsigned int bf16pair(float a, float b) {
  unsigned int ua = __float_as_uint(a), ub = __float_as_uint(b);
  ua = (ua + 0x7FFFu + ((ua >> 16) & 1u)) >> 16;
  ub = (ub + 0x7FFFu + ((ub >> 16) & 1u)) >> 16;
  return ua | (ub << 16);
}

// single-instruction packed f32->bf16 (RTNE)
__device__ __forceinline__ unsigned int cvtpk(float a, float b) {
  unsigned int r;
  asm("v_cvt_pk_bf16_f32 %0, %1, %2" : "=v"(r) : "v"(a), "v"(b));
  return r;
}

__device__ __forceinline__ float elu(float v) {
  return v > 0.f ? v : (__expf(v) - 1.f);
}

// ---------------------------------------------------------------------------
// Prep: W_z [4][128][128] f32 -> bf16 fragment-linear layout.
// uint4 index u = ((kk*4 + ks)*8 + ot)*64 + lane
//   holds W_z[ks][o][h0..h0+7], o = ot*16 + (lane&15), h0 = kk*32 + (lane>>4)*8
// Chunk c = kk*4 + ks = 512 contiguous uint4 = 8KB.
// ---------------------------------------------------------------------------
__global__ void k_prep(const float* __restrict__ Wz, uint4* __restrict__ wfrag) {
  const int u = blockIdx.x * 256 + threadIdx.x;  // 8192 total
  const int lane = u & 63;
  const int ot = (u >> 6) & 7;
  const int ks = (u >> 9) & 3;
  const int kk = u >> 11;
  const int o = ot * 16 + (lane & 15);
  const int h0 = kk * 32 + (lane >> 4) * 8;
  const float4* src = (const float4*)(Wz + ((size_t)(ks * HID + o) * HID + h0));
  float4 f0 = src[0], f1 = src[1];
  uint4 pk;
  pk.x = bf16pair(f0.x, f0.y);
  pk.y = bf16pair(f0.z, f0.w);
  pk.z = bf16pair(f1.x, f1.y);
  pk.w = bf16pair(f1.z, f1.w);
  wfrag[u] = pk;
}

// ---------------------------------------------------------------------------
// Main: one WG (512 thr, 8 waves) per (b,c).  [R11's proven 50us K-loop]
// After writing zsum[bc], last-arriving-WG-per-b (device-scope atomic ticket,
// G16/m20) runs the tail chain inline: z2 = elu(zsum@Wzf^T), c-sum, p, out.
// Saves the k_tail launch + graph gap; tails overlap still-running WGs.
// LDS: sA 64KB + sW 2x8KB = 80KB dynamic only (static would break the
// 2-WG/CU 160KB cap). launch_bounds pins regs at 128 (R7 lesson).
// ---------------------------------------------------------------------------
__global__ __launch_bounds__(512, 4) void k_main(
    const float* __restrict__ x, const int* __restrict__ leaf_idx,
    const uint4* __restrict__ wfrag, const float* __restrict__ Wzf,
    const float* __restrict__ Wp, const float* __restrict__ Wpf,
    float* __restrict__ zsum, int* __restrict__ cnt, float* __restrict__ out) {
  extern __shared__ char smem[];
  char* sA = smem;                     // 65536 B
  uint4* sW = (uint4*)(smem + 65536);  // 2 x 512 uint4 = 16384 B

  const int tid = threadIdx.x;
  const int bc = blockIdx.x;
  const int lane = tid & 63;
  const int l15 = lane & 15;
  const int hi = lane >> 4;
  const int w = tid >> 6;
  const int wr = w >> 1;  // 0..3
  const int wc = w & 1;   // 0..1

  // ---- stage data tile: 2 threads per row (gather + cvt_pk + swizzle) ----
  {
    const int r = tid >> 1, half = tid & 1;
    const int idx = leaf_idx[bc * LL + r];
    const float4* src = (const float4*)(x + (size_t)idx * HID + half * 64);
    const int swz = (r & 15) << 4;
    char* rowp = sA + r * 256;
#pragma unroll
    for (int j = 0; j < 8; ++j) {
      float4 f0 = src[2 * j];
      float4 f1 = src[2 * j + 1];
      uint4 pk;
      pk.x = cvtpk(f0.x, f0.y);
      pk.y = cvtpk(f0.z, f0.w);
      pk.z = cvtpk(f1.x, f1.y);
      pk.w = cvtpk(f1.z, f1.w);
      *(uint4*)(rowp + (((half * 128) + j * 16) ^ swz)) = pk;
    }
  }
  // ---- stage weight chunks 0 and 1 (lane-linear, conflict-free) ----
  sW[tid] = wfrag[tid];
  sW[512 + tid] = wfrag[512 + tid];
  __syncthreads();

  f32x4 acc[4][4];
#pragma unroll
  for (int rt = 0; rt < 4; ++rt)
#pragma unroll
    for (int ot = 0; ot < 4; ++ot) acc[rt][ot] = (f32x4){0.f, 0.f, 0.f, 0.f};

  const int r0 = wr * 64;

#pragma unroll
  for (int c = 0; c < 16; ++c) {
    const int kk = c >> 2, ks = c & 3;
    uint4 pref;
    if (c < 14) pref = wfrag[(c + 2) * 512 + tid];

    const uint4* sWc = sW + (c & 1) * 512;
    const int cb = kk * 64 + hi * 16;
    uint4 af[4];
#pragma unroll
    for (int rt = 0; rt < 4; ++rt) {
      const int row = (r0 + rt * 16 + l15 + ks) & 255;
      af[rt] = *(const uint4*)(sA + row * 256 + (cb ^ ((row & 15) << 4)));
    }
    __builtin_amdgcn_s_setprio(1);
#pragma unroll
    for (int ot2 = 0; ot2 < 4; ++ot2) {
      const uint4 bw = sWc[(wc * 4 + ot2) * 64 + lane];
      const b16x8 bb = __builtin_bit_cast(b16x8, bw);
#pragma unroll
      for (int rt = 0; rt < 4; ++rt)
        acc[rt][ot2] = __builtin_amdgcn_mfma_f32_16x16x32_bf16(
            __builtin_bit_cast(b16x8, af[rt]), bb, acc[rt][ot2], 0, 0, 0);
    }
    __builtin_amdgcn_s_setprio(0);
    __syncthreads();
    if (c < 14) sW[(c & 1) * 512 + tid] = pref;
  }

  // ---- epilogue: elu + sum over this wave's 64 rows, cross-wave reduce ----
  // C/D layout (16x16x32): col = wc*64 + ot2*16 + (lane&15); row = hi*4+q
  float colsum[4];
#pragma unroll
  for (int ot2 = 0; ot2 < 4; ++ot2) {
    float s = 0.f;
#pragma unroll
    for (int rt = 0; rt < 4; ++rt)
#pragma unroll
      for (int q = 0; q < 4; ++q) s += elu(acc[rt][ot2][q]);
    s += __shfl_xor(s, 16);
    s += __shfl_xor(s, 32);
    colsum[ot2] = s;
  }
  float* sRed = (float*)sA;  // sA reads all done (last K-loop barrier)
  if (lane < 16) {
#pragma unroll
    for (int ot2 = 0; ot2 < 4; ++ot2)
      sRed[w * 64 + ot2 * 16 + lane] = colsum[ot2];
  }
  __syncthreads();
  if (tid < 128) {
    const int wc2 = tid >> 6, lc = tid & 63;
    float s = 0.f;
#pragma unroll
    for (int wrr = 0; wrr < 4; ++wrr) s += sRed[(wrr * 2 + wc2) * 64 + lc];
    zsum[bc * 128 + tid] = s;
  }

  // ---- last-arriving-WG-per-b ticket: 16th finisher runs the tail ----
  const int b = bc >> 4;
  __threadfence();      // release our zsum writes (device scope)
  __syncthreads();      // all zsum stores issued before the ticket
  volatile int* sFlag = (volatile int*)(smem + 65536);  // sW region, free now
  if (tid == 0) sFlag[0] = (atomicAdd(&cnt[b], 1) == 15);
  __syncthreads();
  if (!sFlag[0]) return;
  __threadfence();      // acquire: other WGs' zsum writes now visible

  // ================= tail (R11's k_tail body, b = bc>>4) =================
  {
    float* sZ = (float*)smem;            // 8 KB
    float* sS = (float*)(smem + 8192);   // 4 x 128 floats
    float* sV = (float*)(smem + 10240);  // 128 floats
    float* sP = (float*)(smem + 10752);  // 128 floats
    __syncthreads();  // flag consumed; safe to reuse smem
#pragma unroll
    for (int j = 0; j < 4; ++j)
      sZ[tid + j * 512] = zsum[(size_t)b * (CC * HID) + tid + j * 512];
    __syncthreads();

    // z2 + c-sum: o = tid&127, group g2 = tid>>7 owns c = g2*4..g2*4+3
    {
      const int o = tid & 127, g2 = tid >> 7;
      const float4* wr4 = (const float4*)(Wzf + o * HID);
      float d0 = 0.f, d1 = 0.f, d2 = 0.f, d3 = 0.f;
#pragma unroll
      for (int j = 0; j < 32; ++j) {
        const float4 wv = wr4[j];
        const float4 z0 = *(const float4*)(sZ + (g2 * 4 + 0) * HID + j * 4);
        const float4 z1 = *(const float4*)(sZ + (g2 * 4 + 1) * HID + j * 4);
        const float4 z2v = *(const float4*)(sZ + (g2 * 4 + 2) * HID + j * 4);
        const float4 z3 = *(const float4*)(sZ + (g2 * 4 + 3) * HID + j * 4);
        d0 += wv.x * z0.x + wv.y * z0.y + wv.z * z0.z + wv.w * z0.w;
        d1 += wv.x * z1.x + wv.y * z1.y + wv.z * z1.z + wv.w * z1.w;
        d2 += wv.x * z2v.x + wv.y * z2v.y + wv.z * z2v.z + wv.w * z2v.w;
        d3 += wv.x * z3.x + wv.y * z3.y + wv.z * z3.z + wv.w * z3.w;
      }
      sS[g2 * HID + o] = elu(d0) + elu(d1) + elu(d2) + elu(d3);
    }
    __syncthreads();
    if (tid < HID)
      sV[tid] = sS[0 * HID + tid] + sS[1 * HID + tid] + sS[2 * HID + tid] +
                sS[3 * HID + tid];
    __syncthreads();

    // p = sV @ Wp^T : 4 threads per output
    {
      const int o2 = tid >> 2, sub = tid & 3;
      const float4* wp4 = (const float4*)(Wp + o2 * HID + sub * 32);
      const float4* v4 = (const float4*)(sV + sub * 32);
      float d0 = 0.f, d1 = 0.f;
#pragma unroll
      for (int j = 0; j < 8; j += 2) {
        float4 a0 = wp4[j], c0 = v4[j];
        float4 a1 = wp4[j + 1], c1 = v4[j + 1];
        d0 += a0.x * c0.x + a0.y * c0.y + a0.z * c0.z + a0.w * c0.w;
        d1 += a1.x * c1.x + a1.y * c1.y + a1.z * c1.z + a1.w * c1.w;
      }
      float d = d0 + d1;
      d += __shfl_xor(d, 1);
      d += __shfl_xor(d, 2);
      if (sub == 0) sP[o2] = d;
    }
    __syncthreads();

    // out = sP @ Wpf^T : 4 threads per output
    {
      const int o2 = tid >> 2, sub = tid & 3;
      const float4* wp4 = (const float4*)(Wpf + o2 * HID + sub * 32);
      const float4* p4 = (const float4*)(sP + sub * 32);
      float d0 = 0.f, d1 = 0.f;
#pragma unroll
      for (int j = 0; j < 8; j += 2) {
        float4 a0 = wp4[j], c0 = p4[j];
        float4 a1 = wp4[j + 1], c1 = p4[j + 1];
        d0 += a0.x * c0.x + a0.y * c0.y + a0.z * c0.z + a0.w * c0.w;
        d1 += a1.x * c1.x + a1.y * c1.y + a1.z * c1.z + a1.w * c1.w;
      }
      float d = d0 + d1;
      d += __shfl_xor(d, 1);
      d += __shfl_xor(d, 2);
      if (sub == 0) out[b * HID + o2] = d;
    }
  }
}

extern "C" void kernel_launch(void* const* d_in, const int* in_sizes, int n_in,
                              void* d_out, int out_size, void* d_ws, size_t ws_size,
                              hipStream_t stream) {
  const float* x = (const float*)d_in[0];
  const int* leaf = (const int*)d_in[1];
  const float* Wz = (const float*)d_in[2];
  const float* Wzf = (const float*)d_in[3];
  const float* Wp = (const float*)d_in[4];
  const float* Wpf = (const float*)d_in[5];
  float* out = (float*)d_out;

  uint4* wfrag = (uint4*)d_ws;                   // 128 KB
  float* zsum = (float*)((char*)d_ws + 131072);  // 512 KB
  int* cnt = (int*)((char*)d_ws + 655360);       // 256 B

  (void)hipFuncSetAttribute((const void*)k_main,
                            hipFuncAttributeMaxDynamicSharedMemorySize, 81920);

  (void)hipMemsetAsync(cnt, 0, 64 * sizeof(int), stream);
  k_prep<<<32, 256, 0, stream>>>(Wz, wfrag);
  k_main<<<1024, 512, 81920, stream>>>(x, leaf, wfrag, Wzf, Wp, Wpf, zsum, cnt,
                                       out);
}

// Round 14
// 71.178 us; speedup vs baseline: 3.7077x; 3.7077x over previous
//
#include <hip/hip_runtime.h>
#include <hip/hip_bf16.h>

#define N_NODES 100000
#define HID 128
#define BB 64
#define CC 16
#define LL 256

typedef __bf16 b16x8 __attribute__((ext_vector_type(8)));
typedef float f32x4 __attribute__((ext_vector_type(4)));

__device__ __forceinline__ unsigned int bf16pair(float a, float b) {
  unsigned int ua = __float_as_uint(a), ub = __float_as_uint(b);
  ua = (ua + 0x7FFFu + ((ua >> 16) & 1u)) >> 16;
  ub = (ub + 0x7FFFu + ((ub >> 16) & 1u)) >> 16;
  return ua | (ub << 16);
}

// single-instruction packed f32->bf16 (RTNE)
__device__ __forceinline__ unsigned int cvtpk(float a, float b) {
  unsigned int r;
  asm("v_cvt_pk_bf16_f32 %0, %1, %2" : "=v"(r) : "v"(a), "v"(b));
  return r;
}

__device__ __forceinline__ float elu(float v) {
  return v > 0.f ? v : (__expf(v) - 1.f);
}

// ---------------------------------------------------------------------------
// Prep: W_z [4][128][128] f32 -> bf16 fragment-linear layout (unchanged).
// uint4 index u = ((kk*4 + ks)*8 + ot)*64 + lane
//   holds W_z[ks][o][h0..h0+7], o = ot*16 + (lane&15), h0 = kk*32 + (lane>>4)*8
// Chunk c = kk*4 + ks = 512 contiguous uint4 = 8KB.
// ---------------------------------------------------------------------------
__global__ void k_prep(const float* __restrict__ Wz, uint4* __restrict__ wfrag) {
  const int u = blockIdx.x * 256 + threadIdx.x;  // 8192 total
  const int lane = u & 63;
  const int ot = (u >> 6) & 7;
  const int ks = (u >> 9) & 3;
  const int kk = u >> 11;
  const int o = ot * 16 + (lane & 15);
  const int h0 = kk * 32 + (lane >> 4) * 8;
  const float4* src = (const float4*)(Wz + ((size_t)(ks * HID + o) * HID + h0));
  float4 f0 = src[0], f1 = src[1];
  uint4 pk;
  pk.x = bf16pair(f0.x, f0.y);
  pk.y = bf16pair(f0.z, f0.w);
  pk.z = bf16pair(f1.x, f1.y);
  pk.w = bf16pair(f1.z, f1.w);
  wfrag[u] = pk;
}

// ---------------------------------------------------------------------------
// Main: L-SPLIT. One WG (256 thr, 4 waves) per (b,c,half): 2048 WGs.
// Each WG computes rows [half*128, half*128+128) of the roll-GEMM (needs
// rows up to +131 due to the ks roll -> stages 131 local rows, mod-256).
// Wave grid: wr = w>>1 (2 row tiles of 64), wc = w&1 (2 col tiles of 64).
// Wave tile 64x64 -> acc[4][4] = 64 AGPRs (same proven shapes as R11).
// LDS: sA 132x256B = 33KB + sW 2x8KB = 49KB -> 3 WGs/CU (12 waves), reg
// budget ~170/thread (vs the 64-VGPR squeeze at 2x512): 3 decoupled barrier
// groups per CU attack the convoy stalls that cap R11's loop at 50us.
// Halves combine via atomicAdd on zsum (2 commutative f32 adds ->
// bit-deterministic; zsum zeroed by async memset each call).
// K-loop pipeline byte-equivalent to R11 (reg-prefetch 2 ahead, one barrier
// per chunk, setprio around MFMA cluster -- all A/B-proven).
// ---------------------------------------------------------------------------
__global__ __launch_bounds__(256, 3) void k_main(
    const float* __restrict__ x, const int* __restrict__ leaf_idx,
    const uint4* __restrict__ wfrag, float* __restrict__ zsum) {
  extern __shared__ char smem[];
  char* sA = smem;                     // 132 rows x 256 B = 33792 B
  uint4* sW = (uint4*)(smem + 33792);  // 2 x 512 uint4 = 16384 B

  const int tid = threadIdx.x;
  const int bh = blockIdx.x;
  const int bc = bh >> 1;
  const int hbase = (bh & 1) * 128;
  const int lane = tid & 63;
  const int l15 = lane & 15;
  const int hi = lane >> 4;
  const int w = tid >> 6;   // 0..3
  const int wr = w >> 1;    // 0..1
  const int wc = w & 1;     // 0..1

  // ---- stage data rows 0..127 (2 threads per row) ----
  {
    const int rl = tid >> 1, hc = tid & 1;
    const int gr = (hbase + rl) & 255;
    const int idx = leaf_idx[bc * LL + gr];
    const float4* src = (const float4*)(x + (size_t)idx * HID + hc * 64);
    const int swz = (rl & 15) << 4;
    char* rowp = sA + rl * 256;
#pragma unroll
    for (int j = 0; j < 8; ++j) {
      float4 f0 = src[2 * j];
      float4 f1 = src[2 * j + 1];
      uint4 pk;
      pk.x = cvtpk(f0.x, f0.y);
      pk.y = cvtpk(f0.z, f0.w);
      pk.z = cvtpk(f1.x, f1.y);
      pk.w = cvtpk(f1.z, f1.w);
      *(uint4*)(rowp + (((hc * 128) + j * 16) ^ swz)) = pk;
    }
  }
  // ---- stage the 3 roll-overlap rows 128..130 (threads 0..5) ----
  if (tid < 6) {
    const int rl = 128 + (tid >> 1), hc = tid & 1;
    const int gr = (hbase + rl) & 255;
    const int idx = leaf_idx[bc * LL + gr];
    const float4* src = (const float4*)(x + (size_t)idx * HID + hc * 64);
    const int swz = (rl & 15) << 4;
    char* rowp = sA + rl * 256;
#pragma unroll
    for (int j = 0; j < 8; ++j) {
      float4 f0 = src[2 * j];
      float4 f1 = src[2 * j + 1];
      uint4 pk;
      pk.x = cvtpk(f0.x, f0.y);
      pk.y = cvtpk(f0.z, f0.w);
      pk.z = cvtpk(f1.x, f1.y);
      pk.w = cvtpk(f1.z, f1.w);
      *(uint4*)(rowp + (((hc * 128) + j * 16) ^ swz)) = pk;
    }
  }
  // ---- stage weight chunks 0 and 1 (lane-linear, conflict-free) ----
#pragma unroll
  for (int i = 0; i < 2; ++i) {
    sW[tid + i * 256] = wfrag[tid + i * 256];
    sW[512 + tid + i * 256] = wfrag[512 + tid + i * 256];
  }
  __syncthreads();

  f32x4 acc[4][4];
#pragma unroll
  for (int rt = 0; rt < 4; ++rt)
#pragma unroll
    for (int ot = 0; ot < 4; ++ot) acc[rt][ot] = (f32x4){0.f, 0.f, 0.f, 0.f};

  const int r0 = wr * 64;

#pragma unroll
  for (int c = 0; c < 16; ++c) {
    const int kk = c >> 2, ks = c & 3;
    uint4 pref0, pref1;
    if (c < 14) {
      pref0 = wfrag[(c + 2) * 512 + tid];
      pref1 = wfrag[(c + 2) * 512 + tid + 256];
    }

    const uint4* sWc = sW + (c & 1) * 512;
    const int cb = kk * 64 + hi * 16;
    uint4 af[4];
#pragma unroll
    for (int rt = 0; rt < 4; ++rt) {
      const int rr = r0 + rt * 16 + l15 + ks;  // 0..130, no wrap needed
      af[rt] = *(const uint4*)(sA + rr * 256 + (cb ^ ((rr & 15) << 4)));
    }
    __builtin_amdgcn_s_setprio(1);
#pragma unroll
    for (int ot2 = 0; ot2 < 4; ++ot2) {
      const uint4 bw = sWc[(wc * 4 + ot2) * 64 + lane];
      const b16x8 bb = __builtin_bit_cast(b16x8, bw);
#pragma unroll
      for (int rt = 0; rt < 4; ++rt)
        acc[rt][ot2] = __builtin_amdgcn_mfma_f32_16x16x32_bf16(
            __builtin_bit_cast(b16x8, af[rt]), bb, acc[rt][ot2], 0, 0, 0);
    }
    __builtin_amdgcn_s_setprio(0);
    __syncthreads();
    if (c < 14) {
      sW[(c & 1) * 512 + tid] = pref0;
      sW[(c & 1) * 512 + tid + 256] = pref1;
    }
  }

  // ---- epilogue: elu + sum over this wave's 64 rows, cross-wave reduce ----
  // C/D layout (16x16x32): col = wc*64 + ot2*16 + (lane&15); row = hi*4+q
  float colsum[4];
#pragma unroll
  for (int ot2 = 0; ot2 < 4; ++ot2) {
    float s = 0.f;
#pragma unroll
    for (int rt = 0; rt < 4; ++rt)
#pragma unroll
      for (int q = 0; q < 4; ++q) s += elu(acc[rt][ot2][q]);
    s += __shfl_xor(s, 16);
    s += __shfl_xor(s, 32);
    colsum[ot2] = s;
  }
  float* sRed = (float*)sA;  // sA reads all done (last K-loop barrier)
  if (lane < 16) {
#pragma unroll
    for (int ot2 = 0; ot2 < 4; ++ot2)
      sRed[w * 64 + ot2 * 16 + lane] = colsum[ot2];
  }
  __syncthreads();
  if (tid < 128) {
    const int wc2 = tid >> 6, lc = tid & 63;
    // sum over wr in {0,1}: wave index = wr*2 + wc2
    const float s = sRed[(0 * 2 + wc2) * 64 + lc] + sRed[(1 * 2 + wc2) * 64 + lc];
    atomicAdd(&zsum[bc * 128 + tid], s);  // 2 commutative adds: deterministic
  }
}

// ---------------------------------------------------------------------------
// Tail (f32, exact), one block (512 thr) per b  [R11's proven ~3us kernel]:
//   z2[c] = elu(zsum[b,c] @ Wzf^T); s = sum_c z2[c]; p = s @ Wp^T;
//   out = p @ Wpf^T.  Wzf row hoisted (read once per thread).
// ---------------------------------------------------------------------------
__global__ __launch_bounds__(512) void k_tail(
    const float* __restrict__ zsum, const float* __restrict__ Wzf,
    const float* __restrict__ Wp, const float* __restrict__ Wpf,
    float* __restrict__ out) {
  __shared__ float sZ[CC * HID];  // 8KB
  __shared__ float sS[4][HID];
  __shared__ float sV[HID];
  __shared__ float sP[HID];
  const int tid = threadIdx.x, b = blockIdx.x;
#pragma unroll
  for (int j = 0; j < 4; ++j)
    sZ[tid + j * 512] = zsum[(size_t)b * (CC * HID) + tid + j * 512];
  __syncthreads();

  {
    const int o = tid & 127, g = tid >> 7;
    const float4* wr4 = (const float4*)(Wzf + o * HID);
    float d0 = 0.f, d1 = 0.f, d2 = 0.f, d3 = 0.f;
#pragma unroll
    for (int j = 0; j < 32; ++j) {
      const float4 wv = wr4[j];
      const float4 z0 = *(const float4*)(sZ + (g * 4 + 0) * HID + j * 4);
      const float4 z1 = *(const float4*)(sZ + (g * 4 + 1) * HID + j * 4);
      const float4 z2v = *(const float4*)(sZ + (g * 4 + 2) * HID + j * 4);
      const float4 z3 = *(const float4*)(sZ + (g * 4 + 3) * HID + j * 4);
      d0 += wv.x * z0.x + wv.y * z0.y + wv.z * z0.z + wv.w * z0.w;
      d1 += wv.x * z1.x + wv.y * z1.y + wv.z * z1.z + wv.w * z1.w;
      d2 += wv.x * z2v.x + wv.y * z2v.y + wv.z * z2v.z + wv.w * z2v.w;
      d3 += wv.x * z3.x + wv.y * z3.y + wv.z * z3.z + wv.w * z3.w;
    }
    sS[g][tid & 127] = elu(d0) + elu(d1) + elu(d2) + elu(d3);
  }
  __syncthreads();
  if (tid < HID)
    sV[tid] = sS[0][tid] + sS[1][tid] + sS[2][tid] + sS[3][tid];
  __syncthreads();

  {
    const int o2 = tid >> 2, sub = tid & 3;
    const float4* wp4 = (const float4*)(Wp + o2 * HID + sub * 32);
    const float4* v4 = (const float4*)(sV + sub * 32);
    float d0 = 0.f, d1 = 0.f;
#pragma unroll
    for (int j = 0; j < 8; j += 2) {
      float4 a0 = wp4[j], c0 = v4[j];
      float4 a1 = wp4[j + 1], c1 = v4[j + 1];
      d0 += a0.x * c0.x + a0.y * c0.y + a0.z * c0.z + a0.w * c0.w;
      d1 += a1.x * c1.x + a1.y * c1.y + a1.z * c1.z + a1.w * c1.w;
    }
    float d = d0 + d1;
    d += __shfl_xor(d, 1);
    d += __shfl_xor(d, 2);
    if (sub == 0) sP[o2] = d;
  }
  __syncthreads();

  {
    const int o2 = tid >> 2, sub = tid & 3;
    const float4* wp4 = (const float4*)(Wpf + o2 * HID + sub * 32);
    const float4* p4 = (const float4*)(sP + sub * 32);
    float d0 = 0.f, d1 = 0.f;
#pragma unroll
    for (int j = 0; j < 8; j += 2) {
      float4 a0 = wp4[j], c0 = p4[j];
      float4 a1 = wp4[j + 1], c1 = p4[j + 1];
      d0 += a0.x * c0.x + a0.y * c0.y + a0.z * c0.z + a0.w * c0.w;
      d1 += a1.x * c1.x + a1.y * c1.y + a1.z * c1.z + a1.w * c1.w;
    }
    float d = d0 + d1;
    d += __shfl_xor(d, 1);
    d += __shfl_xor(d, 2);
    if (sub == 0) out[b * HID + o2] = d;
  }
}

extern "C" void kernel_launch(void* const* d_in, const int* in_sizes, int n_in,
                              void* d_out, int out_size, void* d_ws, size_t ws_size,
                              hipStream_t stream) {
  const float* x = (const float*)d_in[0];
  const int* leaf = (const int*)d_in[1];
  const float* Wz = (const float*)d_in[2];
  const float* Wzf = (const float*)d_in[3];
  const float* Wp = (const float*)d_in[4];
  const float* Wpf = (const float*)d_in[5];
  float* out = (float*)d_out;

  uint4* wfrag = (uint4*)d_ws;                   // 128 KB
  float* zsum = (float*)((char*)d_ws + 131072);  // 512 KB

  (void)hipFuncSetAttribute((const void*)k_main,
                            hipFuncAttributeMaxDynamicSharedMemorySize, 50176);

  (void)hipMemsetAsync(zsum, 0, 1024 * HID * sizeof(float), stream);
  k_prep<<<32, 256, 0, stream>>>(Wz, wfrag);
  k_main<<<2048, 256, 50176, stream>>>(x, leaf, wfrag, zsum);
  k_tail<<<64, 512, 0, stream>>>(zsum, Wzf, Wp, Wpf, out);
}

// Round 15
// 61.741 us; speedup vs baseline: 4.2744x; 1.1528x over previous
//
#include <hip/hip_runtime.h>
#include <hip/hip_bf16.h>

#define N_NODES 100000
#define HID 128
#define BB 64
#define CC 16
#define LL 256

typedef __bf16 b16x8 __attribute__((ext_vector_type(8)));
typedef float f32x4 __attribute__((ext_vector_type(4)));

__device__ __forceinline__ unsigned int bf16pair(float a, float b) {
  unsigned int ua = __float_as_uint(a), ub = __float_as_uint(b);
  ua = (ua + 0x7FFFu + ((ua >> 16) & 1u)) >> 16;
  ub = (ub + 0x7FFFu + ((ub >> 16) & 1u)) >> 16;
  return ua | (ub << 16);
}

// single-instruction packed f32->bf16 (RTNE)
__device__ __forceinline__ unsigned int cvtpk(float a, float b) {
  unsigned int r;
  asm("v_cvt_pk_bf16_f32 %0, %1, %2" : "=v"(r) : "v"(a), "v"(b));
  return r;
}

__device__ __forceinline__ float elu(float v) {
  return v > 0.f ? v : (__expf(v) - 1.f);
}

// ---------------------------------------------------------------------------
// Prep: W_z [4][128][128] f32 -> bf16 fragment-linear layout.
// uint4 index u = ((kk*4 + ks)*8 + ot)*64 + lane
//   holds W_z[ks][o][h0..h0+7], o = ot*16 + (lane&15), h0 = kk*32 + (lane>>4)*8
// Chunk c = kk*4 + ks = 512 contiguous uint4 = 8KB.
// ---------------------------------------------------------------------------
__global__ void k_prep(const float* __restrict__ Wz, uint4* __restrict__ wfrag) {
  const int u = blockIdx.x * 256 + threadIdx.x;  // 8192 total
  const int lane = u & 63;
  const int ot = (u >> 6) & 7;
  const int ks = (u >> 9) & 3;
  const int kk = u >> 11;
  const int o = ot * 16 + (lane & 15);
  const int h0 = kk * 32 + (lane >> 4) * 8;
  const float4* src = (const float4*)(Wz + ((size_t)(ks * HID + o) * HID + h0));
  float4 f0 = src[0], f1 = src[1];
  uint4 pk;
  pk.x = bf16pair(f0.x, f0.y);
  pk.y = bf16pair(f0.z, f0.w);
  pk.z = bf16pair(f1.x, f1.y);
  pk.w = bf16pair(f1.z, f1.w);
  wfrag[u] = pk;
}

// ---------------------------------------------------------------------------
// Main: one WG (512 thr, 8 waves) per (b,c).  [R11 proven best: 50.5us]
// Wave grid: wr = w>>1 (4 row tiles of 64), wc = w&1 (2 col tiles of 64).
// Wave tile 64x64 -> acc[4][4] = 64 AGPRs. 16 weight chunks (kk,ks) of 8KB,
// double-buffered, ONE barrier per chunk, reg-prefetched 2 chunks ahead:
//   iter c: pref=wfrag[c+2]; compute(c) from buf[c&1]; barrier; buf[c&1]=pref
//   (per-wave vmcnt wait at the ds_write, not a collective barrier drain).
// setprio(1) around MFMA cluster: R4-vs-R8 A/B = +5us on this workload.
// CONSTRAINT BOX (all measured): arch VGPR must stay <=64 (R7: 144 regs ->
// 1 WG/CU -> 110us); LDS 80KB x2 = 160KB cap; no device-scope fences (R13:
// 6x slowdown); no coop launch (R12 rejected); no L-split (R14: staging 2x).
// Epilogue: zsum = sum_l elu(z_pre) -> global; z2 GEMV lives in k_tail.
// LDS: sA 64KB (256x128 bf16, 16B-slot XOR swizzle) + sW 2x8KB = 80KB.
// ---------------------------------------------------------------------------
__global__ __launch_bounds__(512, 4) void k_main(
    const float* __restrict__ x, const int* __restrict__ leaf_idx,
    const uint4* __restrict__ wfrag, float* __restrict__ zsum) {
  extern __shared__ char smem[];
  char* sA = smem;                     // 65536 B
  uint4* sW = (uint4*)(smem + 65536);  // 2 x 512 uint4 = 16384 B

  const int tid = threadIdx.x;
  const int bc = blockIdx.x;
  const int lane = tid & 63;
  const int l15 = lane & 15;
  const int hi = lane >> 4;
  const int w = tid >> 6;
  const int wr = w >> 1;  // 0..3
  const int wc = w & 1;   // 0..1

  // ---- stage data tile: 2 threads per row (gather + cvt_pk + swizzle) ----
  {
    const int r = tid >> 1, half = tid & 1;
    const int idx = leaf_idx[bc * LL + r];
    const float4* src = (const float4*)(x + (size_t)idx * HID + half * 64);
    const int swz = (r & 15) << 4;
    char* rowp = sA + r * 256;
#pragma unroll
    for (int j = 0; j < 8; ++j) {
      float4 f0 = src[2 * j];
      float4 f1 = src[2 * j + 1];
      uint4 pk;
      pk.x = cvtpk(f0.x, f0.y);
      pk.y = cvtpk(f0.z, f0.w);
      pk.z = cvtpk(f1.x, f1.y);
      pk.w = cvtpk(f1.z, f1.w);
      *(uint4*)(rowp + (((half * 128) + j * 16) ^ swz)) = pk;
    }
  }
  // ---- stage weight chunks 0 and 1 (lane-linear, conflict-free) ----
  sW[tid] = wfrag[tid];
  sW[512 + tid] = wfrag[512 + tid];
  __syncthreads();

  f32x4 acc[4][4];
#pragma unroll
  for (int rt = 0; rt < 4; ++rt)
#pragma unroll
    for (int ot = 0; ot < 4; ++ot) acc[rt][ot] = (f32x4){0.f, 0.f, 0.f, 0.f};

  const int r0 = wr * 64;

#pragma unroll
  for (int c = 0; c < 16; ++c) {
    const int kk = c >> 2, ks = c & 3;
    uint4 pref;
    if (c < 14) pref = wfrag[(c + 2) * 512 + tid];

    const uint4* sWc = sW + (c & 1) * 512;
    const int cb = kk * 64 + hi * 16;
    uint4 af[4];
#pragma unroll
    for (int rt = 0; rt < 4; ++rt) {
      const int row = (r0 + rt * 16 + l15 + ks) & 255;
      af[rt] = *(const uint4*)(sA + row * 256 + (cb ^ ((row & 15) << 4)));
    }
    __builtin_amdgcn_s_setprio(1);
#pragma unroll
    for (int ot2 = 0; ot2 < 4; ++ot2) {
      const uint4 bw = sWc[(wc * 4 + ot2) * 64 + lane];
      const b16x8 bb = __builtin_bit_cast(b16x8, bw);
#pragma unroll
      for (int rt = 0; rt < 4; ++rt)
        acc[rt][ot2] = __builtin_amdgcn_mfma_f32_16x16x32_bf16(
            __builtin_bit_cast(b16x8, af[rt]), bb, acc[rt][ot2], 0, 0, 0);
    }
    __builtin_amdgcn_s_setprio(0);
    __syncthreads();
    if (c < 14) sW[(c & 1) * 512 + tid] = pref;
  }

  // ---- epilogue: elu + sum over this wave's 64 rows, cross-wave reduce ----
  // C/D layout (16x16x32): col = wc*64 + ot2*16 + (lane&15); row = hi*4+q
  float colsum[4];
#pragma unroll
  for (int ot2 = 0; ot2 < 4; ++ot2) {
    float s = 0.f;
#pragma unroll
    for (int rt = 0; rt < 4; ++rt)
#pragma unroll
      for (int q = 0; q < 4; ++q) s += elu(acc[rt][ot2][q]);
    s += __shfl_xor(s, 16);
    s += __shfl_xor(s, 32);
    colsum[ot2] = s;
  }
  float* sRed = (float*)sA;  // sA reads all done (last K-loop barrier)
  if (lane < 16) {
#pragma unroll
    for (int ot2 = 0; ot2 < 4; ++ot2)
      sRed[w * 64 + ot2 * 16 + lane] = colsum[ot2];
  }
  __syncthreads();
  if (tid < 128) {
    const int wc2 = tid >> 6, lc = tid & 63;
    float s = 0.f;
#pragma unroll
    for (int wrr = 0; wrr < 4; ++wrr) s += sRed[(wrr * 2 + wc2) * 64 + lc];
    zsum[bc * 128 + tid] = s;
  }
}

// ---------------------------------------------------------------------------
// Tail (f32, exact), one block (512 thr) per b:
//   z2[c] = elu(zsum[b,c] @ Wzf^T); s = sum_c z2[c]; p = s @ Wp^T;
//   out = p @ Wpf^T.  Wzf row hoisted (each thread reads its row once).
// ---------------------------------------------------------------------------
__global__ __launch_bounds__(512) void k_tail(
    const float* __restrict__ zsum, const float* __restrict__ Wzf,
    const float* __restrict__ Wp, const float* __restrict__ Wpf,
    float* __restrict__ out) {
  __shared__ float sZ[CC * HID];  // 8KB
  __shared__ float sS[4][HID];
  __shared__ float sV[HID];
  __shared__ float sP[HID];
  const int tid = threadIdx.x, b = blockIdx.x;
#pragma unroll
  for (int j = 0; j < 4; ++j)
    sZ[tid + j * 512] = zsum[(size_t)b * (CC * HID) + tid + j * 512];
  __syncthreads();

  // z2 + c-sum: o = tid&127, g = tid>>7 owns c = g*4..g*4+3
  {
    const int o = tid & 127, g = tid >> 7;
    const float4* wr4 = (const float4*)(Wzf + o * HID);
    float d0 = 0.f, d1 = 0.f, d2 = 0.f, d3 = 0.f;
#pragma unroll
    for (int j = 0; j < 32; ++j) {
      const float4 wv = wr4[j];
      const float4 z0 = *(const float4*)(sZ + (g * 4 + 0) * HID + j * 4);
      const float4 z1 = *(const float4*)(sZ + (g * 4 + 1) * HID + j * 4);
      const float4 z2v = *(const float4*)(sZ + (g * 4 + 2) * HID + j * 4);
      const float4 z3 = *(const float4*)(sZ + (g * 4 + 3) * HID + j * 4);
      d0 += wv.x * z0.x + wv.y * z0.y + wv.z * z0.z + wv.w * z0.w;
      d1 += wv.x * z1.x + wv.y * z1.y + wv.z * z1.z + wv.w * z1.w;
      d2 += wv.x * z2v.x + wv.y * z2v.y + wv.z * z2v.z + wv.w * z2v.w;
      d3 += wv.x * z3.x + wv.y * z3.y + wv.z * z3.z + wv.w * z3.w;
    }
    sS[g][o] = elu(d0) + elu(d1) + elu(d2) + elu(d3);
  }
  __syncthreads();
  if (tid < HID) sV[tid] = sS[0][tid] + sS[1][tid] + sS[2][tid] + sS[3][tid];
  __syncthreads();

  // p = sV @ Wp^T : 4 threads per output
  {
    const int o2 = tid >> 2, sub = tid & 3;
    const float4* wp4 = (const float4*)(Wp + o2 * HID + sub * 32);
    const float4* v4 = (const float4*)(sV + sub * 32);
    float d0 = 0.f, d1 = 0.f;
#pragma unroll
    for (int j = 0; j < 8; j += 2) {
      float4 a0 = wp4[j], c0 = v4[j];
      float4 a1 = wp4[j + 1], c1 = v4[j + 1];
      d0 += a0.x * c0.x + a0.y * c0.y + a0.z * c0.z + a0.w * c0.w;
      d1 += a1.x * c1.x + a1.y * c1.y + a1.z * c1.z + a1.w * c1.w;
    }
    float d = d0 + d1;
    d += __shfl_xor(d, 1);
    d += __shfl_xor(d, 2);
    if (sub == 0) sP[o2] = d;
  }
  __syncthreads();

  // out = sP @ Wpf^T : 4 threads per output
  {
    const int o2 = tid >> 2, sub = tid & 3;
    const float4* wp4 = (const float4*)(Wpf + o2 * HID + sub * 32);
    const float4* p4 = (const float4*)(sP + sub * 32);
    float d0 = 0.f, d1 = 0.f;
#pragma unroll
    for (int j = 0; j < 8; j += 2) {
      float4 a0 = wp4[j], c0 = p4[j];
      float4 a1 = wp4[j + 1], c1 = p4[j + 1];
      d0 += a0.x * c0.x + a0.y * c0.y + a0.z * c0.z + a0.w * c0.w;
      d1 += a1.x * c1.x + a1.y * c1.y + a1.z * c1.z + a1.w * c1.w;
    }
    float d = d0 + d1;
    d += __shfl_xor(d, 1);
    d += __shfl_xor(d, 2);
    if (sub == 0) out[b * HID + o2] = d;
  }
}

extern "C" void kernel_launch(void* const* d_in, const int* in_sizes, int n_in,
                              void* d_out, int out_size, void* d_ws, size_t ws_size,
                              hipStream_t stream) {
  const float* x = (const float*)d_in[0];
  const int* leaf = (const int*)d_in[1];
  const float* Wz = (const float*)d_in[2];
  const float* Wzf = (const float*)d_in[3];
  const float* Wp = (const float*)d_in[4];
  const float* Wpf = (const float*)d_in[5];
  float* out = (float*)d_out;

  uint4* wfrag = (uint4*)d_ws;                   // 128 KB
  float* zsum = (float*)((char*)d_ws + 131072);  // 512 KB

  (void)hipFuncSetAttribute((const void*)k_main,
                            hipFuncAttributeMaxDynamicSharedMemorySize, 81920);

  k_prep<<<32, 256, 0, stream>>>(Wz, wfrag);
  k_main<<<1024, 512, 81920, stream>>>(x, leaf, wfrag, zsum);
  k_tail<<<64, 512, 0, stream>>>(zsum, Wzf, Wp, Wpf, out);
}